// Round 5
// baseline (808.475 us; speedup 1.0000x reference)
//
#include <hip/hip_runtime.h>

#define GRID 64
#define NVOX (GRID*GRID*GRID)
#define NCLS 20
#define NSEED 512

// ---------------- weight transposes, one launch ----------------
// w1t[(nb*6+ci)*64+oc] = w1[oc][ci][nb];  w2t[(nb*64+ci)*32+oc] = w2[oc][ci][nb]
__global__ void transpose_all(const float* __restrict__ w1, float* __restrict__ w1t,
                              const float* __restrict__ w2, float* __restrict__ w2t) {
    int t = blockIdx.x * 256 + threadIdx.x;
    if (t < 27 * 6 * 64) {
        int oc = t & 63;
        int r  = t >> 6;            // nb*6 + ci
        int nb = r / 6, ci = r % 6;
        w1t[t] = w1[oc * 162 + ci * 27 + nb];
        return;
    }
    t -= 27 * 6 * 64;
    if (t < 27 * 64 * 32) {
        int oc = t & 31;
        int r  = t >> 5;            // nb*64 + ci
        int nb = r >> 6, ci = r & 63;
        w2t[t] = w2[oc * 1728 + ci * 27 + nb];
    }
}

// ---------------- conv1 (6->64) + relu, h1[vox][64]; XCD z-chunked dispatch ----------------
__global__ __launch_bounds__(256) void conv1_kernel(
    const float* __restrict__ feat,   // [6][64][64][64]
    const float* __restrict__ w1t,    // [(nb*6+ci)][64]
    const float* __restrict__ b1,
    float* __restrict__ h1)           // [vox][64]
{
    int B = blockIdx.x;               // 1024
    int c = B & 7, k = B >> 3;        // chunk c on XCD c
    int z = c * 8 + (k >> 4);
    int yt = k & 15;
    int x  = threadIdx.x & 63;
    int y  = yt * 4 + (threadIdx.x >> 6);

    float acc[64];
    #pragma unroll
    for (int o = 0; o < 64; ++o) acc[o] = b1[o];

    #pragma unroll 1
    for (int dz = -1; dz <= 1; ++dz) {
      int nz = z + dz; if ((unsigned)nz >= 64u) continue;     // block-uniform (zero pad)
      #pragma unroll 1
      for (int dy = -1; dy <= 1; ++dy) {
        int ny = y + dy; if ((unsigned)ny >= 64u) continue;   // wave-uniform
        #pragma unroll 1
        for (int dx = -1; dx <= 1; ++dx) {
          int nx = x + dx; bool okx = (unsigned)nx < 64u; int cx = okx ? nx : (nx < 0 ? 0 : 63);
          float m = okx ? 1.0f : 0.0f;
          int nb = (dz + 1) * 9 + (dy + 1) * 3 + (dx + 1);
          int voff = (nz * 64 + ny) * 64 + cx;
          const float* wr = w1t + nb * 6 * 64;   // wave-uniform -> s_load
          #pragma unroll
          for (int ci = 0; ci < 6; ++ci) {
            float v = feat[(size_t)ci * NVOX + voff] * m;
            const float* wc = wr + ci * 64;
            #pragma unroll
            for (int o = 0; o < 64; ++o) acc[o] = fmaf(v, wc[o], acc[o]);
          }
        }
      }
    }

    float* dst = h1 + ((size_t)((z * 64 + y) * 64 + x)) * 64;
    #pragma unroll
    for (int o = 0; o < 64; o += 4) {
        float4 v = make_float4(fmaxf(acc[o], 0.f), fmaxf(acc[o+1], 0.f),
                               fmaxf(acc[o+2], 0.f), fmaxf(acc[o+3], 0.f));
        *reinterpret_cast<float4*>(dst + o) = v;
    }
}

// -------- shared epilogue body (inlined; static indexing only) --------
__device__ __forceinline__ void do_epilog(
    const float* acc, int vox,
    const float* __restrict__ shw,      // LDS: sem_w[640] sem_b[20]@640 off_w[96]@660 off_b[3]@756
    const float4* __restrict__ sseed,   // LDS
    const int* __restrict__ sslab,      // LDS
    const float* __restrict__ points,
    float* __restrict__ out_logits, float* __restrict__ out_off,
    int* __restrict__ iv_out, int* __restrict__ bad_seed)
{
    float f[32];
    #pragma unroll
    for (int o = 0; o < 32; ++o) f[o] = fmaxf(acc[o], 0.f);

    float best = -1e30f; int am = 0;
    #pragma unroll
    for (int cc = 0; cc < NCLS; ++cc) {
        float l = shw[640 + cc];
        #pragma unroll
        for (int q = 0; q < 32; ++q) l = fmaf(f[q], shw[cc * 32 + q], l);
        out_logits[(size_t)vox * NCLS + cc] = l;
        if (l > best) { best = l; am = cc; }     // strict > = first occurrence
    }

    float off[3];
    #pragma unroll
    for (int k3 = 0; k3 < 3; ++k3) {
        float l = shw[756 + k3];
        #pragma unroll
        for (int q = 0; q < 32; ++q) l = fmaf(f[q], shw[660 + k3 * 32 + q], l);
        out_off[(size_t)vox * 3 + k3] = l;
        off[k3] = l;
    }

    float px = points[(size_t)vox * 3 + 0] + off[0];
    float py = points[(size_t)vox * 3 + 1] + off[1];
    float pz = points[(size_t)vox * 3 + 2] + off[2];
    float pp = px * px + py * py + pz * pz;

    float bd2 = 1e30f; int bj = 0;
    #pragma unroll 4
    for (int j = 0; j < NSEED; ++j) {
        float4 s = sseed[j];                    // broadcast, conflict-free
        float dot = px * s.x + py * s.y + pz * s.z;
        float d2  = pp + s.w - 2.0f * dot;
        if (d2 < bd2) { bd2 = d2; bj = j; }     // strict < = first occurrence
    }
    float mind = sqrtf(fmaxf(bd2, 0.f));
    bool valid = mind < 1.5f;

    if (valid && am != sslab[bj]) atomicOr(&bad_seed[bj], 1);
    iv_out[vox] = valid ? bj : -1;
}

// ------- conv2 (64->32): Zd=2 z-blocking, LDS double-buffered weights, fused epilogue -------
// grid 512: c=B&7 -> z-chunk/XCD, k=B>>3: z0 = c*8+(k>>4)*2, yt = k&15.
// Weights: per-tap 8KB tile in LDS (broadcast ds_read, lgkm) ; data rows global (vmcnt).
__global__ __launch_bounds__(256, 2) void conv2_fused_kernel(
    const float* __restrict__ h1,     // [vox][64]
    const float* __restrict__ w2t,    // [(nb*64+ci)][32]
    const float* __restrict__ b2,
    const float* __restrict__ points,
    const float* __restrict__ ann,
    const float* __restrict__ sem_w, const float* __restrict__ sem_b,
    const float* __restrict__ off_w, const float* __restrict__ off_b,
    float* __restrict__ out_logits,
    float* __restrict__ out_off,
    int* __restrict__ iv_out,
    int* __restrict__ bad_seed)
{
    __shared__ float  wl[2][2048];    // double-buffered per-tap weight tile [ci][oc]
    __shared__ float4 sseed[NSEED];
    __shared__ int    sslab[NSEED];
    __shared__ float  shw[760];

    int tid = threadIdx.x;

    for (int i = tid; i < NSEED; i += 256) {
        float4 a = *reinterpret_cast<const float4*>(ann + i * 4);
        sseed[i] = make_float4(a.x, a.y, a.z, a.x*a.x + a.y*a.y + a.z*a.z);
        sslab[i] = (int)a.w;
    }
    for (int i = tid; i < NCLS * 32; i += 256) shw[i] = sem_w[i];
    if (tid < NCLS) shw[640 + tid] = sem_b[tid];
    if (tid < 96)   shw[660 + tid] = off_w[tid];
    if (tid < 3)    shw[756 + tid] = off_b[tid];
    {   // stage tap 0 weights
        float4 g0 = *reinterpret_cast<const float4*>(w2t + tid * 8);
        float4 g1 = *reinterpret_cast<const float4*>(w2t + tid * 8 + 4);
        *reinterpret_cast<float4*>(&wl[0][tid * 8])     = g0;
        *reinterpret_cast<float4*>(&wl[0][tid * 8 + 4]) = g1;
    }
    __syncthreads();

    int B = blockIdx.x;
    int c = B & 7, k = B >> 3;
    int z0 = c * 8 + (k >> 4) * 2;
    int yt = k & 15;
    int x  = tid & 63;
    int y  = yt * 4 + (tid >> 6);     // wave-uniform

    float acc0[32], acc1[32];
    #pragma unroll
    for (int o = 0; o < 32; ++o) { acc0[o] = b2[o]; acc1[o] = b2[o]; }

    int cur = 0;
    #pragma unroll 1
    for (int nb = 0; nb < 27; ++nb) {
        // T14: issue next tap's weight loads early (vmcnt), ds_write after compute
        float4 s0, s1;
        if (nb < 26) {
            s0 = *reinterpret_cast<const float4*>(w2t + (nb + 1) * 2048 + tid * 8);
            s1 = *reinterpret_cast<const float4*>(w2t + (nb + 1) * 2048 + tid * 8 + 4);
        }
        int dz  = nb / 9 - 1;
        int rem = nb % 9;
        int dy  = rem / 3 - 1, dx = rem % 3 - 1;
        int ny  = y + dy;
        if ((unsigned)ny < 64u) {                 // wave-uniform skip (zero pad)
            int nz0 = z0 + dz, nz1 = nz0 + 1;
            float mz0 = ((unsigned)nz0 < 64u) ? 1.f : 0.f;
            float mz1 = ((unsigned)nz1 < 64u) ? 1.f : 0.f;
            int cz0 = nz0 < 0 ? 0 : (nz0 > 63 ? 63 : nz0);
            int cz1 = nz1 < 0 ? 0 : (nz1 > 63 ? 63 : nz1);
            int nx = x + dx;
            float mx = ((unsigned)nx < 64u) ? 1.f : 0.f;
            int cx = nx < 0 ? 0 : (nx > 63 ? 63 : nx);
            const float4* src0 = reinterpret_cast<const float4*>(h1 + ((size_t)((cz0 * 64 + ny) * 64 + cx)) * 64);
            const float4* src1 = reinterpret_cast<const float4*>(h1 + ((size_t)((cz1 * 64 + ny) * 64 + cx)) * 64);
            float m0 = mx * mz0, m1 = mx * mz1;

            float4 a0[4], a1[4];                  // current 16-ci row chunks (both z)
            #pragma unroll
            for (int q = 0; q < 4; ++q) { a0[q] = src0[q]; a1[q] = src1[q]; }

            #pragma unroll
            for (int cq = 0; cq < 4; ++cq) {
                float4 n0[4], n1[4];
                if (cq < 3) {                     // prefetch next chunk
                    #pragma unroll
                    for (int q = 0; q < 4; ++q) { n0[q] = src0[(cq+1)*4 + q]; n1[q] = src1[(cq+1)*4 + q]; }
                }
                const float* wb = &wl[cur][cq * 512];
                #pragma unroll
                for (int i4 = 0; i4 < 4; ++i4) {
                    const float* rr0 = reinterpret_cast<const float*>(&a0[i4]);
                    const float* rr1 = reinterpret_cast<const float*>(&a1[i4]);
                    #pragma unroll
                    for (int e = 0; e < 4; ++e) {
                        float v0 = rr0[e] * m0;
                        float v1 = rr1[e] * m1;
                        const float* wc = wb + (i4 * 4 + e) * 32;
                        #pragma unroll
                        for (int o4 = 0; o4 < 8; ++o4) {   // 1 ds_read_b128 : 8 FMA
                            float4 w = *reinterpret_cast<const float4*>(wc + o4 * 4);
                            acc0[o4*4+0] = fmaf(v0, w.x, acc0[o4*4+0]);
                            acc0[o4*4+1] = fmaf(v0, w.y, acc0[o4*4+1]);
                            acc0[o4*4+2] = fmaf(v0, w.z, acc0[o4*4+2]);
                            acc0[o4*4+3] = fmaf(v0, w.w, acc0[o4*4+3]);
                            acc1[o4*4+0] = fmaf(v1, w.x, acc1[o4*4+0]);
                            acc1[o4*4+1] = fmaf(v1, w.y, acc1[o4*4+1]);
                            acc1[o4*4+2] = fmaf(v1, w.z, acc1[o4*4+2]);
                            acc1[o4*4+3] = fmaf(v1, w.w, acc1[o4*4+3]);
                        }
                    }
                }
                if (cq < 3) {
                    #pragma unroll
                    for (int q = 0; q < 4; ++q) { a0[q] = n0[q]; a1[q] = n1[q]; }
                }
            }
        }
        if (nb < 26) {
            *reinterpret_cast<float4*>(&wl[cur ^ 1][tid * 8])     = s0;
            *reinterpret_cast<float4*>(&wl[cur ^ 1][tid * 8 + 4]) = s1;
        }
        __syncthreads();                          // all barriers wave-convergent
        cur ^= 1;
    }

    int vox0 = (z0 * 64 + y) * 64 + x;
    int vox1 = ((z0 + 1) * 64 + y) * 64 + x;
    do_epilog(acc0, vox0, shw, sseed, sslab, points, out_logits, out_off, iv_out, bad_seed);
    do_epilog(acc1, vox1, shw, sseed, sslab, points, out_logits, out_off, iv_out, bad_seed);
}

// ---------------- finalize pseudo labels ----------------
__global__ void finalize_kernel(const int* __restrict__ iv,
                                const int* __restrict__ bad,
                                float* __restrict__ pl) {
    int t = blockIdx.x * 256 + threadIdx.x;
    if (t >= NVOX) return;
    int v = iv[t];
    float r = -1.0f;
    if (v >= 0 && bad[v] == 0) r = (float)v;
    pl[t] = r;
}

extern "C" void kernel_launch(void* const* d_in, const int* in_sizes, int n_in,
                              void* d_out, int out_size, void* d_ws, size_t ws_size,
                              hipStream_t stream) {
    const float* points   = (const float*)d_in[0];
    const float* features = (const float*)d_in[1];
    const float* ann      = (const float*)d_in[2];
    const float* w1       = (const float*)d_in[3];
    const float* b1       = (const float*)d_in[4];
    const float* w2       = (const float*)d_in[5];
    const float* b2       = (const float*)d_in[6];
    const float* sem_w    = (const float*)d_in[7];
    const float* sem_b    = (const float*)d_in[8];
    const float* off_w    = (const float*)d_in[9];
    const float* off_b    = (const float*)d_in[10];

    float* out        = (float*)d_out;
    float* out_logits = out;
    float* out_off    = out + (size_t)NVOX * NCLS;   // N*20
    float* out_pl     = out + (size_t)NVOX * 23;     // N*23

    // workspace layout (bytes, 256-aligned)
    char*  ws  = (char*)d_ws;
    float* w1t = (float*)(ws);                 //    41472 B
    float* w2t = (float*)(ws + 41472);         //   221184 B
    int*   bad = (int*)  (ws + 262656);        //     2048 B
    int*   iv  = (int*)  (ws + 264704);        //  1048576 B
    float* h1  = (float*)(ws + 1313280);       // 67108864 B  (total ~65.3 MB)

    hipMemsetAsync(bad, 0, NSEED * sizeof(int), stream);
    transpose_all<<<257, 256, 0, stream>>>(w1, w1t, w2, w2t);
    conv1_kernel<<<1024, 256, 0, stream>>>(features, w1t, b1, h1);
    conv2_fused_kernel<<<512, 256, 0, stream>>>(h1, w2t, b2, points, ann,
        sem_w, sem_b, off_w, off_b, out_logits, out_off, iv, bad);
    finalize_kernel<<<1024, 256, 0, stream>>>(iv, bad, out_pl);
}

// Round 6
// 568.346 us; speedup vs baseline: 1.4225x; 1.4225x over previous
//
#include <hip/hip_runtime.h>

#define GRID 64
#define NVOX (GRID*GRID*GRID)
#define NCLS 20
#define NSEED 512

// ---------------- weight transposes, one launch ----------------
// w1t[(nb*6+ci)*64+oc] = w1[oc][ci][nb];  w2t[(nb*64+ci)*32+oc] = w2[oc][ci][nb]
__global__ void transpose_all(const float* __restrict__ w1, float* __restrict__ w1t,
                              const float* __restrict__ w2, float* __restrict__ w2t) {
    int t = blockIdx.x * 256 + threadIdx.x;
    if (t < 27 * 6 * 64) {
        int oc = t & 63;
        int r  = t >> 6;            // nb*6 + ci
        int nb = r / 6, ci = r % 6;
        w1t[t] = w1[oc * 162 + ci * 27 + nb];
        return;
    }
    t -= 27 * 6 * 64;
    if (t < 27 * 64 * 32) {
        int oc = t & 31;
        int r  = t >> 5;            // nb*64 + ci
        int nb = r >> 6, ci = r & 63;
        w2t[t] = w2[oc * 1728 + ci * 27 + nb];
    }
}

// ------- conv1 (6->64) + relu -> h1p[32 pair-planes][vox][2] (channel-pair-major) -------
__global__ __launch_bounds__(256) void conv1_kernel(
    const float* __restrict__ feat,   // [6][64][64][64]
    const float* __restrict__ w1t,    // [(nb*6+ci)][64]
    const float* __restrict__ b1,
    float* __restrict__ h1p)          // [32][NVOX][2]
{
    int B = blockIdx.x;               // 1024
    int c = B & 7, k = B >> 3;        // z-chunk c -> XCD c
    int z = c * 8 + (k >> 4);
    int yt = k & 15;
    int x  = threadIdx.x & 63;
    int y  = yt * 4 + (threadIdx.x >> 6);

    float acc[64];
    #pragma unroll
    for (int o = 0; o < 64; ++o) acc[o] = b1[o];

    #pragma unroll 1
    for (int dz = -1; dz <= 1; ++dz) {
      int nz = z + dz; if ((unsigned)nz >= 64u) continue;     // block-uniform (zero pad)
      #pragma unroll 1
      for (int dy = -1; dy <= 1; ++dy) {
        int ny = y + dy; if ((unsigned)ny >= 64u) continue;   // wave-uniform
        #pragma unroll 1
        for (int dx = -1; dx <= 1; ++dx) {
          int nx = x + dx; bool okx = (unsigned)nx < 64u; int cx = okx ? nx : (nx < 0 ? 0 : 63);
          float m = okx ? 1.0f : 0.0f;
          int nb = (dz + 1) * 9 + (dy + 1) * 3 + (dx + 1);
          int voff = (nz * 64 + ny) * 64 + cx;
          const float* wr = w1t + nb * 6 * 64;   // wave-uniform -> s_load
          #pragma unroll
          for (int ci = 0; ci < 6; ++ci) {
            float v = feat[(size_t)ci * NVOX + voff] * m;
            const float* wc = wr + ci * 64;
            #pragma unroll
            for (int o = 0; o < 64; ++o) acc[o] = fmaf(v, wc[o], acc[o]);
          }
        }
      }
    }

    int vox = (z * 64 + y) * 64 + x;
    #pragma unroll
    for (int p = 0; p < 32; ++p) {
        float2 v2 = make_float2(fmaxf(acc[2*p], 0.f), fmaxf(acc[2*p+1], 0.f));
        *reinterpret_cast<float2*>(h1p + ((size_t)p * NVOX + vox) * 2) = v2;
    }
}

// ------- conv2 (64->32): Zd=8, oc-group 8, all-tap weights in LDS, barrier-free K-loop -------
// grid 512: zg = B&7 (-> XCD), k=B>>3: og = k>>4 (0..3), yt = k&15.
__global__ __launch_bounds__(256, 2) void conv2_kernel(
    const float* __restrict__ h1p,    // [32][NVOX][2]
    const float* __restrict__ w2t,    // [(nb*64+ci)][32]
    const float* __restrict__ b2,
    float* __restrict__ pf)           // [vox][32] post-relu
{
    __shared__ float lw[27 * 64 * 8];  // this og's weights, all taps: [(nb*64+ci)][8oc] = 54KB

    int tid = threadIdx.x;
    int B = blockIdx.x;
    int zg = B & 7;
    int k  = B >> 3;
    int og = k >> 4;                   // oc-group (8 oc)
    int yt = k & 15;

    for (int t = tid; t < 27 * 64 * 8; t += 256)
        lw[t] = w2t[(t >> 3) * 32 + og * 8 + (t & 7)];
    __syncthreads();                   // the only barrier

    int x  = tid & 63;
    int ly = tid >> 6;                 // wave id
    int y  = yt * 4 + ly;              // wave-uniform
    int z0 = zg * 8;

    float acc[8][8];
    #pragma unroll
    for (int zz = 0; zz < 8; ++zz)
        #pragma unroll
        for (int o = 0; o < 8; ++o) acc[zz][o] = 0.f;

    // block-uniform z-row window [z0-1, z0+9)
    size_t zoff[10]; float mzv[10];
    #pragma unroll
    for (int rz = 0; rz < 10; ++rz) {
        int gz = z0 - 1 + rz;
        int cz = gz < 0 ? 0 : (gz > 63 ? 63 : gz);
        zoff[rz] = (size_t)cz * 4096;                  // voxels
        mzv[rz] = ((unsigned)gz < 64u) ? 1.f : 0.f;
    }

    #pragma unroll 1
    for (int dydx = 0; dydx < 9; ++dydx) {
        int dy = dydx / 3 - 1;
        int dx = dydx % 3 - 1;
        int ny = y + dy;
        if ((unsigned)ny >= 64u) continue;             // wave-uniform (zero pad), no barriers inside
        int nx = x + dx;
        float mx = ((unsigned)nx < 64u) ? 1.f : 0.f;
        int cx = nx < 0 ? 0 : (nx > 63 ? 63 : nx);
        int rowvox = ny * 64 + cx;

        float cm[10];
        #pragma unroll
        for (int rz = 0; rz < 10; ++rz) cm[rz] = mx * mzv[rz];

        #pragma unroll 1
        for (int cq = 0; cq < 32; ++cq) {              // ci-pairs
            const float* plane = h1p + (size_t)cq * (NVOX * 2);
            float2 v[10];
            #pragma unroll
            for (int rz = 0; rz < 10; ++rz) {
                float2 t2 = *reinterpret_cast<const float2*>(plane + (zoff[rz] + rowvox) * 2);
                v[rz] = make_float2(t2.x * cm[rz], t2.y * cm[rz]);
            }
            #pragma unroll
            for (int dzi = 0; dzi < 3; ++dzi) {        // dz = dzi-1; row rz feeds zl = rz-dzi
                const float4* wp = reinterpret_cast<const float4*>(
                    &lw[(((dzi * 9 + dydx) * 64) + cq * 2) * 8]);
                float4 w0 = wp[0], w1 = wp[1];         // ci0: oc0-3, oc4-7
                float4 w2 = wp[2], w3 = wp[3];         // ci1: oc0-3, oc4-7
                #pragma unroll
                for (int r = 0; r < 8; ++r) {
                    float2 a = v[r + dzi];
                    acc[r][0] = fmaf(a.x, w0.x, acc[r][0]);
                    acc[r][1] = fmaf(a.x, w0.y, acc[r][1]);
                    acc[r][2] = fmaf(a.x, w0.z, acc[r][2]);
                    acc[r][3] = fmaf(a.x, w0.w, acc[r][3]);
                    acc[r][4] = fmaf(a.x, w1.x, acc[r][4]);
                    acc[r][5] = fmaf(a.x, w1.y, acc[r][5]);
                    acc[r][6] = fmaf(a.x, w1.z, acc[r][6]);
                    acc[r][7] = fmaf(a.x, w1.w, acc[r][7]);
                    acc[r][0] = fmaf(a.y, w2.x, acc[r][0]);
                    acc[r][1] = fmaf(a.y, w2.y, acc[r][1]);
                    acc[r][2] = fmaf(a.y, w2.z, acc[r][2]);
                    acc[r][3] = fmaf(a.y, w2.w, acc[r][3]);
                    acc[r][4] = fmaf(a.y, w3.x, acc[r][4]);
                    acc[r][5] = fmaf(a.y, w3.y, acc[r][5]);
                    acc[r][6] = fmaf(a.y, w3.z, acc[r][6]);
                    acc[r][7] = fmaf(a.y, w3.w, acc[r][7]);
                }
            }
        }
    }

    // bias + relu + store 8 voxels x 8 oc
    float bias[8];
    #pragma unroll
    for (int o = 0; o < 8; ++o) bias[o] = b2[og * 8 + o];
    #pragma unroll
    for (int zl = 0; zl < 8; ++zl) {
        int vox = ((z0 + zl) * 64 + y) * 64 + x;
        float* dst = pf + (size_t)vox * 32 + og * 8;
        float4 s0 = make_float4(fmaxf(acc[zl][0] + bias[0], 0.f), fmaxf(acc[zl][1] + bias[1], 0.f),
                                fmaxf(acc[zl][2] + bias[2], 0.f), fmaxf(acc[zl][3] + bias[3], 0.f));
        float4 s1 = make_float4(fmaxf(acc[zl][4] + bias[4], 0.f), fmaxf(acc[zl][5] + bias[5], 0.f),
                                fmaxf(acc[zl][6] + bias[6], 0.f), fmaxf(acc[zl][7] + bias[7], 0.f));
        *reinterpret_cast<float4*>(dst)     = s0;
        *reinterpret_cast<float4*>(dst + 4) = s1;
    }
}

// ------- epilogue: heads + argmax + argmin over seeds + mismatch scatter -------
__global__ __launch_bounds__(256) void epilogue_kernel(
    const float* __restrict__ pf,     // [vox][32] post-relu
    const float* __restrict__ points, // [N][3]
    const float* __restrict__ ann,    // [512][4]
    const float* __restrict__ sem_w, const float* __restrict__ sem_b,
    const float* __restrict__ off_w, const float* __restrict__ off_b,
    float* __restrict__ out_logits,   // [N][20]
    float* __restrict__ out_off,      // [N][3]
    int* __restrict__ iv_out,         // [N]
    int* __restrict__ bad_seed)       // [512]
{
    __shared__ float4 sseed[NSEED];
    for (int i = threadIdx.x; i < NSEED; i += 256) {
        float4 a = *reinterpret_cast<const float4*>(ann + i * 4);
        sseed[i] = make_float4(a.x, a.y, a.z, a.x*a.x + a.y*a.y + a.z*a.z);
    }
    __syncthreads();

    int vox = blockIdx.x * 256 + threadIdx.x;

    float f[32];
    #pragma unroll
    for (int q = 0; q < 8; ++q) {
        float4 v = *reinterpret_cast<const float4*>(pf + (size_t)vox * 32 + q * 4);
        f[q*4+0] = v.x; f[q*4+1] = v.y; f[q*4+2] = v.z; f[q*4+3] = v.w;
    }

    // semantic head + argmax (strict > = first occurrence)
    float best = -1e30f; int am = 0;
    #pragma unroll
    for (int cc = 0; cc < NCLS; ++cc) {
        float l = sem_b[cc];
        #pragma unroll
        for (int q = 0; q < 32; ++q) l = fmaf(f[q], sem_w[cc * 32 + q], l);
        out_logits[(size_t)vox * NCLS + cc] = l;
        if (l > best) { best = l; am = cc; }
    }

    // offset head
    float off[3];
    #pragma unroll
    for (int k3 = 0; k3 < 3; ++k3) {
        float l = off_b[k3];
        #pragma unroll
        for (int q = 0; q < 32; ++q) l = fmaf(f[q], off_w[k3 * 32 + q], l);
        out_off[(size_t)vox * 3 + k3] = l;
        off[k3] = l;
    }

    float px = points[(size_t)vox * 3 + 0] + off[0];
    float py = points[(size_t)vox * 3 + 1] + off[1];
    float pz = points[(size_t)vox * 3 + 2] + off[2];
    float pp = px * px + py * py + pz * pz;

    float bd2 = 1e30f; int bj = 0;
    #pragma unroll 4
    for (int j = 0; j < NSEED; ++j) {
        float4 s = sseed[j];                    // broadcast, conflict-free
        float dot = px * s.x + py * s.y + pz * s.z;
        float d2  = pp + s.w - 2.0f * dot;
        if (d2 < bd2) { bd2 = d2; bj = j; }     // strict < = first occurrence
    }
    float mind = sqrtf(fmaxf(bd2, 0.f));
    bool valid = mind < 1.5f;

    int slab = (int)ann[bj * 4 + 3];
    if (valid && am != slab) atomicOr(&bad_seed[bj], 1);
    iv_out[vox] = valid ? bj : -1;
}

// ---------------- finalize pseudo labels ----------------
__global__ void finalize_kernel(const int* __restrict__ iv,
                                const int* __restrict__ bad,
                                float* __restrict__ pl) {
    int t = blockIdx.x * 256 + threadIdx.x;
    if (t >= NVOX) return;
    int v = iv[t];
    float r = -1.0f;
    if (v >= 0 && bad[v] == 0) r = (float)v;
    pl[t] = r;
}

extern "C" void kernel_launch(void* const* d_in, const int* in_sizes, int n_in,
                              void* d_out, int out_size, void* d_ws, size_t ws_size,
                              hipStream_t stream) {
    const float* points   = (const float*)d_in[0];
    const float* features = (const float*)d_in[1];
    const float* ann      = (const float*)d_in[2];
    const float* w1       = (const float*)d_in[3];
    const float* b1       = (const float*)d_in[4];
    const float* w2       = (const float*)d_in[5];
    const float* b2       = (const float*)d_in[6];
    const float* sem_w    = (const float*)d_in[7];
    const float* sem_b    = (const float*)d_in[8];
    const float* off_w    = (const float*)d_in[9];
    const float* off_b    = (const float*)d_in[10];

    float* out        = (float*)d_out;
    float* out_logits = out;
    float* out_off    = out + (size_t)NVOX * NCLS;   // N*20
    float* out_pl     = out + (size_t)NVOX * 23;     // N*23

    // workspace layout (bytes, 256-aligned)
    char*  ws  = (char*)d_ws;
    float* w1t = (float*)(ws);                 //    41472 B
    float* w2t = (float*)(ws + 41472);         //   221184 B
    int*   bad = (int*)  (ws + 262656);        //     2048 B
    int*   iv  = (int*)  (ws + 264704);        //  1048576 B
    float* pf  = (float*)(ws + 1313280);       // 33554432 B
    float* h1p = (float*)(ws + 34867712);      // 67108864 B  (total ~97.3 MB)

    hipMemsetAsync(bad, 0, NSEED * sizeof(int), stream);
    transpose_all<<<257, 256, 0, stream>>>(w1, w1t, w2, w2t);
    conv1_kernel<<<1024, 256, 0, stream>>>(features, w1t, b1, h1p);
    conv2_kernel<<<512, 256, 0, stream>>>(h1p, w2t, b2, pf);
    epilogue_kernel<<<1024, 256, 0, stream>>>(pf, points, ann,
        sem_w, sem_b, off_w, off_b, out_logits, out_off, iv, bad);
    finalize_kernel<<<1024, 256, 0, stream>>>(iv, bad, out_pl);
}